// Round 10
// baseline (1177.839 us; speedup 1.0000x reference)
//
#include <hip/hip_runtime.h>
#include <hip/hip_fp16.h>

#define HID   300
#define NEIP  304            // nei row stride (f16), mult of 16
#define PSTR  900            // packed row stride in f16 (3 slots x 300)
#define APB   4              // atoms per block in edge_csr

typedef _Float16 f16;
typedef f16  f16x2 __attribute__((ext_vector_type(2)));
typedef f16  f16x4 __attribute__((ext_vector_type(4)));
typedef float f32x4 __attribute__((ext_vector_type(4)));

// ---------------------------------------------------------------------------
// helpers
// ---------------------------------------------------------------------------
__device__ __forceinline__ f16x2 u2h(unsigned u) {
    union { unsigned u; f16x2 h; } c; c.u = u; return c.h;
}
__device__ __forceinline__ unsigned pk16(float a, float b) {
    union { f16 h[2]; unsigned u; } c; c.h[0] = (f16)a; c.h[1] = (f16)b;
    return c.u;
}

// ---------------------------------------------------------------------------
__global__ __launch_bounds__(256) void fill_f32(float* __restrict__ p, int n, float v)
{
    int i = blockIdx.x * blockDim.x + threadIdx.x;
    int stride = gridDim.x * blockDim.x;
    for (; i < n; i += stride) p[i] = v;
}

__global__ __launch_bounds__(256) void zero_i32(int* __restrict__ p, int n)
{
    int i = blockIdx.x * blockDim.x + threadIdx.x;
    int stride = gridDim.x * blockDim.x;
    for (; i < n; i += stride) p[i] = 0;
}

// dst [dstRows][kpad] f16 zero-padded; src fp32 [srcRows][ldsrc], kuse cols used
__global__ __launch_bounds__(256) void cvt_pad_f16(
    f16* __restrict__ dst, const float* __restrict__ src,
    int srcRows, int ldsrc, int kuse, int kpad, int dstRows)
{
    int i = blockIdx.x * 256 + threadIdx.x;
    const int total = dstRows * kpad;
    const int st = gridDim.x * 256;
    for (; i < total; i += st) {
        int r = i / kpad, k = i - r * kpad;
        dst[i] = (r < srcRows && k < kuse) ? (f16)src[(size_t)r * ldsrc + k]
                                           : (f16)0.f;
    }
}

// ---------------------------------------------------------------------------
// CSR build: histogram -> hierarchical scan -> scatter (+ ea permute to f16)
// ---------------------------------------------------------------------------
__global__ __launch_bounds__(256) void hist_tgt(
    const int* __restrict__ tgt, int* __restrict__ deg, int E, int N)
{
    int e = blockIdx.x * 256 + threadIdx.x;
    const int st = gridDim.x * 256;
    for (; e < E; e += st) {
        int t = tgt[e];
        t = ((unsigned)t < (unsigned)N) ? t : 0;
        atomicAdd(&deg[t], 1);
    }
}

// phase 1: per-block (1024 elems) tree reduce -> bsum[blockIdx]
__global__ __launch_bounds__(1024) void scan_p1(
    const int* __restrict__ deg, int* __restrict__ bsum, int N)
{
    __shared__ int s[1024];
    const int t = threadIdx.x;
    const int i = blockIdx.x * 1024 + t;
    s[t] = (i < N) ? deg[i] : 0;
    __syncthreads();
#pragma unroll
    for (int off = 512; off > 0; off >>= 1) {
        if (t < off) s[t] += s[t + off];
        __syncthreads();
    }
    if (t == 0) bsum[blockIdx.x] = s[0];
}

// phase 2: single block exclusive-scan of G (<=1024) block sums -> boff
__global__ __launch_bounds__(1024) void scan_p2(
    const int* __restrict__ bsum, int* __restrict__ boff,
    int G, int* __restrict__ rowPtrN, int E)
{
    __shared__ int s[1024];
    const int t = threadIdx.x;
    s[t] = (t < G) ? bsum[t] : 0;
    __syncthreads();
    for (int off = 1; off < 1024; off <<= 1) {
        const int v = (t >= off) ? s[t - off] : 0;
        __syncthreads();
        s[t] += v;
        __syncthreads();
    }
    if (t < G) boff[t] = (t == 0) ? 0 : s[t - 1];
    if (t == 0) *rowPtrN = E;
}

// phase 3: per-block Hillis-Steele scan + boff -> rowPtr, cursor (exclusive)
__global__ __launch_bounds__(1024) void scan_p3(
    const int* __restrict__ deg, const int* __restrict__ boff,
    int* __restrict__ rowPtr, int* __restrict__ cursor, int N)
{
    __shared__ int s[1024];
    const int t = threadIdx.x;
    const int i = blockIdx.x * 1024 + t;
    const int v = (i < N) ? deg[i] : 0;
    s[t] = v;
    __syncthreads();
    for (int off = 1; off < 1024; off <<= 1) {
        const int w = (t >= off) ? s[t - off] : 0;
        __syncthreads();
        s[t] += w;
        __syncthreads();
    }
    if (i < N) {
        const int excl = boff[blockIdx.x] + s[t] - v;
        rowPtr[i] = excl;
        cursor[i] = excl;
    }
}

__global__ __launch_bounds__(256) void scatter_e(
    const int* __restrict__ src, const int* __restrict__ tgt,
    const float* __restrict__ ea,
    int* __restrict__ cursor, int* __restrict__ csrc,
    unsigned* __restrict__ eaPk,    // [E][8] u32 (14 f16 + pad)
    int E, int N)
{
    int e = blockIdx.x * 256 + threadIdx.x;
    const int st = gridDim.x * 256;
    for (; e < E; e += st) {
        int t = tgt[e];
        int s = src[e];
        t = ((unsigned)t < (unsigned)N) ? t : 0;
        s = ((unsigned)s < (unsigned)N) ? s : 0;
        const int p = atomicAdd(&cursor[t], 1);
        csrc[p] = s;
        const float* er = ea + (size_t)e * 14;
        uint4 q0, q1;
        q0.x = pk16(er[0],  er[1]);  q0.y = pk16(er[2],  er[3]);
        q0.z = pk16(er[4],  er[5]);  q0.w = pk16(er[6],  er[7]);
        q1.x = pk16(er[8],  er[9]);  q1.y = pk16(er[10], er[11]);
        q1.z = pk16(er[12], er[13]); q1.w = 0u;
        uint4* dst = (uint4*)(eaPk + (size_t)p * 8);
        dst[0] = q0;
        dst[1] = q1;
    }
}

// ---------------------------------------------------------------------------
// MFMA GEMM (two-phase): C = act( A1@W1^T + A2@W2^T + bias ), 300 out cols.
// A fp32 (guarded, Kuse cols) or f16 (unguarded, padded rows, stride lda).
// W f16 [320][kpad] zero-padded. C: f16, row stride ldc, cols n<300 written.
// Block: 512 thr = 8 waves, BM=128, BK=16.
// Pipeline (T14 async split, depth 2):
//   - W fragments: direct global->reg per wave, prefetched 1 step ahead
//     (no LDS for W; it is L2-resident and tiny).
//   - A tile: global->reg at step s+2, reg->LDS write AFTER the MFMAs of
//     step s (so no vmcnt stall sits between ds_read and MFMA).
//   - one barrier per K-step, LDS = 10 KB (A double buffer only).
// ---------------------------------------------------------------------------
__global__ __launch_bounds__(512) void gemm_mfma(
    const void* __restrict__ A1, int lda1, int a1f16, int K1use,
    const f16* __restrict__ W1, int kpad1,
    const void* __restrict__ A2, int lda2, int a2f16, int K2use,
    const f16* __restrict__ W2, int kpad2,
    const float* __restrict__ bias,
    f16* __restrict__ C, int ldc,
    int M, int do_relu)
{
    __shared__ f16 As[2][128][20];

    const int tid  = threadIdx.x;
    const int bm   = blockIdx.x * 128;
    const int lane = tid & 63;
    const int wv   = tid >> 6;          // 0..7
    const int wrow = (wv >> 2) * 64;    // 0 / 64
    const int wcol = (wv & 3) * 80;     // 0/80/160/240
    const int lm   = lane & 15;
    const int lk   = (lane >> 4) << 2;

    const int n1 = A1 ? (kpad1 >> 4) : 0;
    const int n2 = A2 ? (kpad2 >> 4) : 0;
    const int ntot = n1 + n2;

    f32x4 acc[4][5];
#pragma unroll
    for (int r = 0; r < 4; ++r)
#pragma unroll
        for (int c = 0; c < 5; ++c) acc[r][c] = (f32x4){0.f, 0.f, 0.f, 0.f};

    const int arow = tid >> 2;          // 0..127
    const int akg  = (tid & 3) << 2;    // 0/4/8/12
    const int gm   = bm + arow;

    // A tile: global -> registers (f16 convert); per-element guard on fp32
    auto a_load = [&](int s) -> f16x4 {
        const void* A; int lda, af16, Kuse, k0;
        if (s < n1) { A = A1; lda = lda1; af16 = a1f16; Kuse = K1use; k0 = s << 4; }
        else        { A = A2; lda = lda2; af16 = a2f16; Kuse = K2use; k0 = (s - n1) << 4; }
        const int gk = k0 + akg;
        f16x4 v = (f16x4){0, 0, 0, 0};
        if (gm < M) {
            if (af16) {
                v = *(const f16x4*)((const f16*)A + (size_t)gm * lda + gk);
            } else {
                const float* p = (const float*)A + (size_t)gm * lda + gk;
#pragma unroll
                for (int j = 0; j < 4; ++j)
                    v[j] = (gk + j < Kuse) ? (f16)p[j] : (f16)0.f;
            }
        }
        return v;
    };

    // W fragments: direct global -> registers (W zero-padded to 320 rows)
    auto w_load = [&](int s, f16x4* bf) {
        const f16* W; int kpad, k0;
        if (s < n1) { W = W1; kpad = kpad1; k0 = s << 4; }
        else        { W = W2; kpad = kpad2; k0 = (s - n1) << 4; }
#pragma unroll
        for (int c = 0; c < 5; ++c)
            bf[c] = *(const f16x4*)(W + (size_t)(wcol + (c << 4) + lm) * kpad
                                      + k0 + lk);
    };

    // ---- prologue: tile 0 into LDS, W(0) into regs, A(1) into regs --------
    f16x4 aReg = a_load(0);
    *(f16x4*)&As[0][arow][akg] = aReg;
    f16x4 bfCur[5];
    w_load(0, bfCur);
    if (ntot > 1) aReg = a_load(1);
    __syncthreads();

    int b = 0;
    for (int s = 0; s < ntot; ++s) {
        // 1) fragments of current tile (ds_read; only dependency of MFMA)
        f16x4 af[4];
#pragma unroll
        for (int r = 0; r < 4; ++r)
            af[r] = *(const f16x4*)&As[b][wrow + (r << 4) + lm][lk];
        // 2) prefetch W(s+1) and A(s+2) into registers (no waits here)
        f16x4 bfNext[5];
        if (s + 1 < ntot) w_load(s + 1, bfNext);
        f16x4 aNext = aReg;
        if (s + 2 < ntot) aNext = a_load(s + 2);
        // 3) MFMA on current fragments
#pragma unroll
        for (int r = 0; r < 4; ++r)
#pragma unroll
            for (int c = 0; c < 5; ++c)
                acc[r][c] = __builtin_amdgcn_mfma_f32_16x16x16f16(
                    af[r], bfCur[c], acc[r][c], 0, 0, 0);
        // 4) write tile s+1 (loaded one full step ago) into the other buffer
        if (s + 1 < ntot) {
            *(f16x4*)&As[b ^ 1][arow][akg] = aReg;
#pragma unroll
            for (int c = 0; c < 5; ++c) bfCur[c] = bfNext[c];
        }
        __syncthreads();
        aReg = aNext;
        b ^= 1;
    }

    // epilogue: C/D frag col = lane&15, row = 4*(lane>>4)+i ; only n<300 stored
#pragma unroll
    for (int r = 0; r < 4; ++r) {
        const int gm0 = bm + wrow + (r << 4) + ((lane >> 4) << 2);
#pragma unroll
        for (int c = 0; c < 5; ++c) {
            const int n = wcol + (c << 4) + lm;
            if (n >= HID) continue;
            const float bi = bias ? bias[n] : 0.f;
#pragma unroll
            for (int i = 0; i < 4; ++i) {
                const int gmo = gm0 + i;
                if (gmo >= M) continue;
                float v = acc[r][c][i] + bi;
                if (do_relu) v = fmaxf(v, 0.f);
                C[(size_t)gmo * ldc + n] = (f16)v;
            }
        }
    }
}

// ---------------------------------------------------------------------------
// edge_csr: per target atom, accumulate messages of incoming edges in fp32
// registers, store one coalesced row. Packed-f16 math, no atomics.
//   m = relu(packed[s,0] + eaPk[j] @ Wb^T); relu(+packed[s,1]); relu(+packed[s,2])
// Block handles APB atoms; thread p = channel pair (2p, 2p+1).
// ---------------------------------------------------------------------------
template <int NSLOTS>
__global__ __launch_bounds__(192) void edge_csr(
    const unsigned* __restrict__ packed,  // [N][450] u32 pairs (slots +0/+150/+300)
    const int* __restrict__ rowPtr,
    const int* __restrict__ csrc,
    const unsigned* __restrict__ eaPk,    // [E][8] u32 (14 f16)
    const float* __restrict__ Wi,         // [300,147] fp32 (bond cols 133..146)
    unsigned* __restrict__ out,           // nei [N][152] u32 pairs
    int N)
{
    const int p = threadIdx.x;
    f16x2 wpk[14];
    if (p < 150) {
#pragma unroll
        for (int k = 0; k < 14; ++k)
            wpk[k] = (f16x2){(f16)Wi[(2 * p) * 147 + 133 + k],
                             (f16)Wi[(2 * p + 1) * 147 + 133 + k]};
    }
    const f16x2 zero2 = (f16x2){(f16)0.f, (f16)0.f};

    const int a0 = blockIdx.x * APB;
    const int a1 = min(a0 + APB, N);
    for (int a = a0; a < a1; ++a) {
        const int beg = rowPtr[a];
        const int end = rowPtr[a + 1];
        float acc0 = 0.f, acc1 = 0.f;
        if (p < 150) {
#pragma unroll 2
            for (int j = beg; j < end; ++j) {
                const int s = csrc[j];
                const unsigned* row = packed + (size_t)s * (PSTR / 2);
                const unsigned u0 = row[p];
                unsigned u1 = 0, u2 = 0;
                if (NSLOTS > 1) u1 = row[p + 150];
                if (NSLOTS > 2) u2 = row[p + 300];
                const unsigned* eq = eaPk + (size_t)j * 8;
                f16x2 ebA = zero2, ebB = zero2;
#pragma unroll
                for (int k = 0; k < 7; ++k) {
                    const f16x2 e2 = u2h(eq[k]);
                    ebA += (f16x2){e2.x, e2.x} * wpk[2 * k];
                    ebB += (f16x2){e2.y, e2.y} * wpk[2 * k + 1];
                }
                f16x2 m = __builtin_elementwise_max(u2h(u0) + (ebA + ebB), zero2);
                if (NSLOTS > 1) m = __builtin_elementwise_max(m + u2h(u1), zero2);
                if (NSLOTS > 2) m = __builtin_elementwise_max(m + u2h(u2), zero2);
                acc0 += (float)m.x;
                acc1 += (float)m.y;
            }
        }
        if (p < NEIP / 2)
            out[(size_t)a * (NEIP / 2) + p] = (p < 150) ? pk16(acc0, acc1) : 0u;
    }
}

// ---------------------------------------------------------------------------
// mol_pool: mol[b,:300] = sum of atom_h rows (f16, stride PSTR) with batch==b
// ---------------------------------------------------------------------------
__global__ __launch_bounds__(256) void mol_pool(
    const f16* __restrict__ ah,       // packed slot1: [N] rows stride 900
    const int* __restrict__ batch,    // [N], sorted
    float* __restrict__ mol,          // [B,300]
    int N)
{
    const int b = blockIdx.x;
    int lo = 0, hi = N;
    while (lo < hi) { int mid = (lo + hi) >> 1; if (batch[mid] < b) lo = mid + 1; else hi = mid; }
    const int start = lo;
    hi = N;
    while (lo < hi) { int mid = (lo + hi) >> 1; if (batch[mid] < b + 1) lo = mid + 1; else hi = mid; }
    const int end = lo;

    for (int h = threadIdx.x; h < HID; h += 256) {
        float s = 0.f;
        for (int a = start; a < end; ++a) s += (float)ah[(size_t)a * PSTR + h];
        mol[(size_t)b * HID + h] = s;
    }
}

// ---------------------------------------------------------------------------
__global__ __launch_bounds__(64) void ffn2_k(
    const f16* __restrict__ h1,       // [B][304] f16
    const float* __restrict__ w2,     // [300]
    const float* __restrict__ b2, float* __restrict__ out, int B)
{
    const int b = blockIdx.x;
    float s = 0.f;
    for (int k = threadIdx.x; k < HID; k += 64)
        s += (float)h1[(size_t)b * NEIP + k] * w2[k];
#pragma unroll
    for (int off = 32; off > 0; off >>= 1) s += __shfl_down(s, off);
    if (threadIdx.x == 0) out[b] = s + b2[0];
}

// ---------------------------------------------------------------------------
extern "C" void kernel_launch(void* const* d_in, const int* in_sizes, int n_in,
                              void* d_out, int out_size, void* d_ws, size_t ws_size,
                              hipStream_t stream)
{
    float* outp = (float*)d_out;
    const int fillBlocks = (out_size + 255) / 256;

    if (n_in < 12) {
        fill_f32<<<fillBlocks, 256, 0, stream>>>(outp, out_size, 2.0e6f + n_in);
        return;
    }

    const int N = in_sizes[0] / 133;   // atoms
    const int E = in_sizes[1] / 2;     // edges
    const int B = out_size;            // molecules

    const long long expect[12] = {
        (long long)N * 133, (long long)E * 2, (long long)E * 14, N,
        300LL * 147, 300LL * 300, 300LL * 433, 300,
        300LL * 300, 300, 300, 1 };
    for (int i = 0; i < 12; ++i) {
        if ((long long)in_sizes[i] != expect[i]) {
            fill_f32<<<fillBlocks, 256, 0, stream>>>(outp, out_size,
                                                     3.0e6f + 1.0e4f * i);
            return;
        }
    }

    const int G = (N + 1023) / 1024;   // scan blocks (N=100K -> 98)
    if (G > 1024) {
        fill_f32<<<fillBlocks, 256, 0, stream>>>(outp, out_size, 4.0e6f);
        return;
    }

    // ---- workspace layout ---------------------------------------------------
    char* basep = (char*)d_ws;
    auto align16 = [](size_t v) { return (v + 15) & ~(size_t)15; };
    const size_t packedB = align16((size_t)N * PSTR * sizeof(f16));
    const size_t neiB    = align16((size_t)N * NEIP * sizeof(f16));
    const size_t wSmall  = align16(320 * 144 * sizeof(f16));
    const size_t wBig    = align16(320 * 304 * sizeof(f16));
    const size_t molB    = align16((size_t)B * HID * sizeof(float));
    const size_t h1B     = align16((size_t)B * NEIP * sizeof(f16));
    const size_t rpB     = align16((size_t)(N + 1) * sizeof(int));
    const size_t curB    = align16((size_t)N * sizeof(int));
    const size_t csrcB   = align16((size_t)E * sizeof(int));
    const size_t eaB     = align16((size_t)E * 8 * sizeof(unsigned));
    const size_t bsB     = align16(1024 * sizeof(int));
    const size_t need = packedB + neiB + 2 * wSmall + 3 * wBig
                      + molB + h1B + rpB + 2 * curB + csrcB + eaB + 2 * bsB;

    if (ws_size < need) {
        fill_f32<<<fillBlocks, 256, 0, stream>>>(outp, out_size,
                                                 (float)(ws_size >> 20));
        return;
    }

    const float* x     = (const float*)d_in[0];
    const int*   ei    = (const int*)d_in[1];
    const float* ea    = (const float*)d_in[2];
    const int*   batch = (const int*)d_in[3];
    const float* W_i   = (const float*)d_in[4];
    const float* W_h   = (const float*)d_in[5];
    const float* W_o   = (const float*)d_in[6];
    const float* W_ob  = (const float*)d_in[7];
    const float* f1w   = (const float*)d_in[8];
    const float* f1b   = (const float*)d_in[9];
    const float* f2w   = (const float*)d_in[10];
    const float* f2b   = (const float*)d_in[11];
    const int* src = ei;
    const int* tgt = ei + E;

    char* cp = basep;
    f16* packed = (f16*)cp;         cp += packedB;
    f16* nei    = (f16*)cp;         cp += neiB;
    f16* WiA    = (f16*)cp;         cp += wSmall;
    f16* Wh     = (f16*)cp;         cp += wBig;
    f16* WoA    = (f16*)cp;         cp += wSmall;
    f16* WoB    = (f16*)cp;         cp += wBig;
    f16* Wf1    = (f16*)cp;         cp += wBig;
    float* mol  = (float*)cp;       cp += molB;
    f16* h1     = (f16*)cp;         cp += h1B;
    int* rowPtr = (int*)cp;         cp += rpB;
    int* cursor = (int*)cp;         cp += curB;
    int* deg    = (int*)cp;         cp += curB;
    int* csrc   = (int*)cp;         cp += csrcB;
    unsigned* eaPk = (unsigned*)cp; cp += eaB;
    int* bsum   = (int*)cp;         cp += bsB;
    int* boff   = (int*)cp;         cp += bsB;

    f16* xa_s  = packed;          // slot 0
    f16* hn0_s = packed + 300;    // slot 1 (later atom_h)
    f16* hn1_s = packed + 600;    // slot 2

    const unsigned* packed_u = (const unsigned*)packed;
    unsigned*       nei_u    = (unsigned*)nei;

    const int gAtom = (N + 127) / 128;
    const int gMolG = (B + 127) / 128;
    const int gEdge = (N + APB - 1) / APB;

    // --- CSR build (+ permuted f16 bond features) ---
    zero_i32<<<128, 256, 0, stream>>>(deg, N);
    hist_tgt<<<1024, 256, 0, stream>>>(tgt, deg, E, N);
    scan_p1<<<G, 1024, 0, stream>>>(deg, bsum, N);
    scan_p2<<<1, 1024, 0, stream>>>(bsum, boff, G, rowPtr + N, E);
    scan_p3<<<G, 1024, 0, stream>>>(deg, boff, rowPtr, cursor, N);
    scatter_e<<<1024, 256, 0, stream>>>(src, tgt, ea, cursor, csrc, eaPk, E, N);

    // --- weights -> padded f16 ---
    cvt_pad_f16<<<64,  256, 0, stream>>>(WiA, W_i,       300, 147, 133, 144, 320);
    cvt_pad_f16<<<128, 256, 0, stream>>>(Wh,  W_h,       300, 300, 300, 304, 320);
    cvt_pad_f16<<<64,  256, 0, stream>>>(WoA, W_o,       300, 433, 133, 144, 320);
    cvt_pad_f16<<<128, 256, 0, stream>>>(WoB, W_o + 133, 300, 433, 300, 304, 320);
    cvt_pad_f16<<<128, 256, 0, stream>>>(Wf1, f1w,       300, 300, 300, 304, 320);

    // 1. xa = x @ W_i[:, :133]^T -> packed slot0
    gemm_mfma<<<gAtom, 512, 0, stream>>>(x, 133, 0, 133, WiA, 144,
        nullptr, 0, 0, 0, nullptr, 0, nullptr, xa_s, PSTR, N, 0);
    // 2. nei0 = segsum(m0)
    edge_csr<1><<<gEdge, 192, 0, stream>>>(packed_u, rowPtr, csrc, eaPk, W_i,
                                           nei_u, N);
    // 3. hn0 = nei0 @ W_h^T -> packed slot1
    gemm_mfma<<<gAtom, 512, 0, stream>>>(nei, NEIP, 1, NEIP, Wh, 304,
        nullptr, 0, 0, 0, nullptr, 0, nullptr, hn0_s, PSTR, N, 0);
    // 4. nei1 = segsum(m1)
    edge_csr<2><<<gEdge, 192, 0, stream>>>(packed_u, rowPtr, csrc, eaPk, W_i,
                                           nei_u, N);
    // 5. hn1 = nei1 @ W_h^T -> packed slot2
    gemm_mfma<<<gAtom, 512, 0, stream>>>(nei, NEIP, 1, NEIP, Wh, 304,
        nullptr, 0, 0, 0, nullptr, 0, nullptr, hn1_s, PSTR, N, 0);
    // 6. atom_msg = segsum(m2)
    edge_csr<3><<<gEdge, 192, 0, stream>>>(packed_u, rowPtr, csrc, eaPk, W_i,
                                           nei_u, N);
    // 7. atom_h = relu(x @ WoA^T + msg @ WoB^T + b) -> packed slot1
    gemm_mfma<<<gAtom, 512, 0, stream>>>(x, 133, 0, 133, WoA, 144,
        nei, NEIP, 1, NEIP, WoB, 304, W_ob, hn0_s, PSTR, N, 1);
    // 8. mol[b] = segment_sum(atom_h)
    mol_pool<<<B, 256, 0, stream>>>(hn0_s, batch, mol, N);
    // 9. h1 = relu(mol @ ffn1^T + b1)   (MFMA, f16 out)
    gemm_mfma<<<gMolG, 512, 0, stream>>>(mol, 300, 0, 300, Wf1, 304,
        nullptr, 0, 0, 0, nullptr, 0, f1b, h1, NEIP, B, 1);
    // 10. out = h1 @ ffn2^T + b2
    ffn2_k<<<B, 64, 0, stream>>>(h1, f2w, f2b, outp, B);
}

// Round 11
// 846.212 us; speedup vs baseline: 1.3919x; 1.3919x over previous
//
#include <hip/hip_runtime.h>
#include <hip/hip_fp16.h>

#define HID   300
#define NEIP  304            // nei row stride (f16), mult of 16
#define PSTR  900            // packed row stride in f16 (3 slots x 300)
#define APB   4              // atoms per block in edge_csr

typedef _Float16 f16;
typedef f16  f16x2 __attribute__((ext_vector_type(2)));
typedef f16  f16x4 __attribute__((ext_vector_type(4)));
typedef float f32x4 __attribute__((ext_vector_type(4)));

// ---------------------------------------------------------------------------
// helpers
// ---------------------------------------------------------------------------
__device__ __forceinline__ f16x2 u2h(unsigned u) {
    union { unsigned u; f16x2 h; } c; c.u = u; return c.h;
}
__device__ __forceinline__ unsigned pk16(float a, float b) {
    union { f16 h[2]; unsigned u; } c; c.h[0] = (f16)a; c.h[1] = (f16)b;
    return c.u;
}

// ---------------------------------------------------------------------------
__global__ __launch_bounds__(256) void fill_f32(float* __restrict__ p, int n, float v)
{
    int i = blockIdx.x * blockDim.x + threadIdx.x;
    int stride = gridDim.x * blockDim.x;
    for (; i < n; i += stride) p[i] = v;
}

__global__ __launch_bounds__(256) void zero_i32(int* __restrict__ p, int n)
{
    int i = blockIdx.x * blockDim.x + threadIdx.x;
    int stride = gridDim.x * blockDim.x;
    for (; i < n; i += stride) p[i] = 0;
}

// dst [dstRows][kpad] f16 zero-padded; src fp32 [srcRows][ldsrc], kuse cols used
__global__ __launch_bounds__(256) void cvt_pad_f16(
    f16* __restrict__ dst, const float* __restrict__ src,
    int srcRows, int ldsrc, int kuse, int kpad, int dstRows)
{
    int i = blockIdx.x * 256 + threadIdx.x;
    const int total = dstRows * kpad;
    const int st = gridDim.x * 256;
    for (; i < total; i += st) {
        int r = i / kpad, k = i - r * kpad;
        dst[i] = (r < srcRows && k < kuse) ? (f16)src[(size_t)r * ldsrc + k]
                                           : (f16)0.f;
    }
}

// ---------------------------------------------------------------------------
// CSR build: histogram -> hierarchical scan -> scatter (+ ea permute to f16)
// ---------------------------------------------------------------------------
__global__ __launch_bounds__(256) void hist_tgt(
    const int* __restrict__ tgt, int* __restrict__ deg, int E, int N)
{
    int e = blockIdx.x * 256 + threadIdx.x;
    const int st = gridDim.x * 256;
    for (; e < E; e += st) {
        int t = tgt[e];
        t = ((unsigned)t < (unsigned)N) ? t : 0;
        atomicAdd(&deg[t], 1);
    }
}

// phase 1: per-block (1024 elems) tree reduce -> bsum[blockIdx]
__global__ __launch_bounds__(1024) void scan_p1(
    const int* __restrict__ deg, int* __restrict__ bsum, int N)
{
    __shared__ int s[1024];
    const int t = threadIdx.x;
    const int i = blockIdx.x * 1024 + t;
    s[t] = (i < N) ? deg[i] : 0;
    __syncthreads();
#pragma unroll
    for (int off = 512; off > 0; off >>= 1) {
        if (t < off) s[t] += s[t + off];
        __syncthreads();
    }
    if (t == 0) bsum[blockIdx.x] = s[0];
}

// phase 2: single block exclusive-scan of G (<=1024) block sums -> boff
__global__ __launch_bounds__(1024) void scan_p2(
    const int* __restrict__ bsum, int* __restrict__ boff,
    int G, int* __restrict__ rowPtrN, int E)
{
    __shared__ int s[1024];
    const int t = threadIdx.x;
    s[t] = (t < G) ? bsum[t] : 0;
    __syncthreads();
    for (int off = 1; off < 1024; off <<= 1) {
        const int v = (t >= off) ? s[t - off] : 0;
        __syncthreads();
        s[t] += v;
        __syncthreads();
    }
    if (t < G) boff[t] = (t == 0) ? 0 : s[t - 1];
    if (t == 0) *rowPtrN = E;
}

// phase 3: per-block Hillis-Steele scan + boff -> rowPtr, cursor (exclusive)
__global__ __launch_bounds__(1024) void scan_p3(
    const int* __restrict__ deg, const int* __restrict__ boff,
    int* __restrict__ rowPtr, int* __restrict__ cursor, int N)
{
    __shared__ int s[1024];
    const int t = threadIdx.x;
    const int i = blockIdx.x * 1024 + t;
    const int v = (i < N) ? deg[i] : 0;
    s[t] = v;
    __syncthreads();
    for (int off = 1; off < 1024; off <<= 1) {
        const int w = (t >= off) ? s[t - off] : 0;
        __syncthreads();
        s[t] += w;
        __syncthreads();
    }
    if (i < N) {
        const int excl = boff[blockIdx.x] + s[t] - v;
        rowPtr[i] = excl;
        cursor[i] = excl;
    }
}

__global__ __launch_bounds__(256) void scatter_e(
    const int* __restrict__ src, const int* __restrict__ tgt,
    const float* __restrict__ ea,
    int* __restrict__ cursor, int* __restrict__ csrc,
    unsigned* __restrict__ eaPk,    // [E][8] u32 (14 f16 + pad)
    int E, int N)
{
    int e = blockIdx.x * 256 + threadIdx.x;
    const int st = gridDim.x * 256;
    for (; e < E; e += st) {
        int t = tgt[e];
        int s = src[e];
        t = ((unsigned)t < (unsigned)N) ? t : 0;
        s = ((unsigned)s < (unsigned)N) ? s : 0;
        const int p = atomicAdd(&cursor[t], 1);
        csrc[p] = s;
        const float* er = ea + (size_t)e * 14;
        uint4 q0, q1;
        q0.x = pk16(er[0],  er[1]);  q0.y = pk16(er[2],  er[3]);
        q0.z = pk16(er[4],  er[5]);  q0.w = pk16(er[6],  er[7]);
        q1.x = pk16(er[8],  er[9]);  q1.y = pk16(er[10], er[11]);
        q1.z = pk16(er[12], er[13]); q1.w = 0u;
        uint4* dst = (uint4*)(eaPk + (size_t)p * 8);
        dst[0] = q0;
        dst[1] = q1;
    }
}

// ---------------------------------------------------------------------------
// MFMA GEMM (two-phase): C = act( A1@W1^T + A2@W2^T + bias ), 300 out cols.
// A fp32 (guarded, Kuse cols) or f16 (unguarded, padded rows, stride lda).
// W f16 [320][kpad], zero-padded. C: f16, row stride ldc, cols n<300 written.
// Block: 512 thr = 8 waves, BM=128, BK=16, double-buffered LDS for A AND W.
// T14 load-early/write-late pipeline:
//   step s: ds_read frags(s) -> issue global loads (s+2) -> MFMA(s)
//           -> regs(s+1) -> LDS (their loads landed a full step ago) -> barrier
// So MFMA waits only on lgkmcnt; no vmcnt stall sits on the critical path.
// ---------------------------------------------------------------------------
__global__ __launch_bounds__(512) void gemm_mfma(
    const void* __restrict__ A1, int lda1, int a1f16, int K1use,
    const f16* __restrict__ W1, int kpad1,
    const void* __restrict__ A2, int lda2, int a2f16, int K2use,
    const f16* __restrict__ W2, int kpad2,
    const float* __restrict__ bias,
    f16* __restrict__ C, int ldc,
    int M, int do_relu)
{
    __shared__ f16 As[2][128][20];
    __shared__ f16 Ws[2][320][20];

    const int tid  = threadIdx.x;
    const int bm   = blockIdx.x * 128;
    const int lane = tid & 63;
    const int wv   = tid >> 6;          // 0..7
    const int wrow = (wv >> 2) * 64;    // 0 / 64
    const int wcol = (wv & 3) * 80;     // 0/80/160/240
    const int lm   = lane & 15;
    const int lk   = (lane >> 4) << 2;

    const int n1 = A1 ? (kpad1 >> 4) : 0;
    const int n2 = A2 ? (kpad2 >> 4) : 0;
    const int ntot = n1 + n2;

    f32x4 acc[4][5];
#pragma unroll
    for (int r = 0; r < 4; ++r)
#pragma unroll
        for (int c = 0; c < 5; ++c) acc[r][c] = (f32x4){0.f, 0.f, 0.f, 0.f};

    const int arow = tid >> 2;          // 0..127
    const int akg  = (tid & 3) << 2;    // 0/4/8/12
    const int gm   = bm + arow;

    // A tile: global -> registers (f16 convert); per-element guard on fp32
    auto a_load = [&](int s) -> f16x4 {
        const void* A; int lda, af16, Kuse, k0;
        if (s < n1) { A = A1; lda = lda1; af16 = a1f16; Kuse = K1use; k0 = s << 4; }
        else        { A = A2; lda = lda2; af16 = a2f16; Kuse = K2use; k0 = (s - n1) << 4; }
        const int gk = k0 + akg;
        f16x4 v = (f16x4){0, 0, 0, 0};
        if (gm < M) {
            if (af16) {
                v = *(const f16x4*)((const f16*)A + (size_t)gm * lda + gk);
            } else {
                const float* p = (const float*)A + (size_t)gm * lda + gk;
#pragma unroll
                for (int j = 0; j < 4; ++j)
                    v[j] = (gk + j < Kuse) ? (f16)p[j] : (f16)0.f;
            }
        }
        return v;
    };

    // W tile: global -> registers, coalesced (4 tids cover one 32B row chunk)
    auto w_load = [&](int s, f16x4* w) {
        const f16* W; int kpad, k0;
        if (s < n1) { W = W1; kpad = kpad1; k0 = s << 4; }
        else        { W = W2; kpad = kpad2; k0 = (s - n1) << 4; }
#pragma unroll
        for (int it = 0; it < 3; ++it) {
            const int idx = tid + (it << 9);
            if (idx < 1280) {
                const int wr = idx >> 2, kg = (idx & 3) << 2;
                w[it] = *(const f16x4*)(W + (size_t)wr * kpad + k0 + kg);
            }
        }
    };

    auto stage_write = [&](int b, f16x4 a, const f16x4* w) {
        *(f16x4*)&As[b][arow][akg] = a;
#pragma unroll
        for (int it = 0; it < 3; ++it) {
            const int idx = tid + (it << 9);
            if (idx < 1280) {
                const int wr = idx >> 2, kg = (idx & 3) << 2;
                *(f16x4*)&Ws[b][wr][kg] = w[it];
            }
        }
    };

    // ---- prologue: tile 0 -> LDS[0]; tile 1 -> regs ------------------------
    const f16x4 z4 = (f16x4){0, 0, 0, 0};
    f16x4 aNxt = z4, wNxt[3] = {z4, z4, z4};
    {
        f16x4 a0 = a_load(0);
        f16x4 w0[3] = {z4, z4, z4};
        w_load(0, w0);
        stage_write(0, a0, w0);
        if (ntot > 1) { aNxt = a_load(1); w_load(1, wNxt); }
    }
    __syncthreads();

    int b = 0;
    for (int s = 0; s < ntot; ++s) {
        // 1) fragments of current tile (ds_read; the only MFMA dependency)
        f16x4 af[4], bf[5];
#pragma unroll
        for (int r = 0; r < 4; ++r)
            af[r] = *(const f16x4*)&As[b][wrow + (r << 4) + lm][lk];
#pragma unroll
        for (int c = 0; c < 5; ++c)
            bf[c] = *(const f16x4*)&Ws[b][wcol + (c << 4) + lm][lk];
        // 2) issue tile s+2 global loads into registers (no waits)
        f16x4 aN2 = z4, wN2[3] = {z4, z4, z4};
        if (s + 2 < ntot) { aN2 = a_load(s + 2); w_load(s + 2, wN2); }
        // 3) MFMA on current fragments
#pragma unroll
        for (int r = 0; r < 4; ++r)
#pragma unroll
            for (int c = 0; c < 5; ++c)
                acc[r][c] = __builtin_amdgcn_mfma_f32_16x16x16f16(
                    af[r], bf[c], acc[r][c], 0, 0, 0);
        // 4) write tile s+1 (loaded one full step ago) into the other buffer
        if (s + 1 < ntot) {
            stage_write(b ^ 1, aNxt, wNxt);
            aNxt = aN2;
#pragma unroll
            for (int it = 0; it < 3; ++it) wNxt[it] = wN2[it];
        }
        __syncthreads();
        b ^= 1;
    }

    // epilogue: C/D frag col = lane&15, row = 4*(lane>>4)+i ; only n<300 stored
#pragma unroll
    for (int r = 0; r < 4; ++r) {
        const int gm0 = bm + wrow + (r << 4) + ((lane >> 4) << 2);
#pragma unroll
        for (int c = 0; c < 5; ++c) {
            const int n = wcol + (c << 4) + lm;
            if (n >= HID) continue;
            const float bi = bias ? bias[n] : 0.f;
#pragma unroll
            for (int i = 0; i < 4; ++i) {
                const int gmo = gm0 + i;
                if (gmo >= M) continue;
                float v = acc[r][c][i] + bi;
                if (do_relu) v = fmaxf(v, 0.f);
                C[(size_t)gmo * ldc + n] = (f16)v;
            }
        }
    }
}

// ---------------------------------------------------------------------------
// edge_csr: per target atom, accumulate messages of incoming edges in fp32
// registers, store one coalesced row. Packed-f16 math, no atomics.
//   m = relu(packed[s,0] + eaPk[j] @ Wb^T); relu(+packed[s,1]); relu(+packed[s,2])
// Block handles APB atoms; thread p = channel pair (2p, 2p+1).
// ---------------------------------------------------------------------------
template <int NSLOTS>
__global__ __launch_bounds__(192) void edge_csr(
    const unsigned* __restrict__ packed,  // [N][450] u32 pairs (slots +0/+150/+300)
    const int* __restrict__ rowPtr,
    const int* __restrict__ csrc,
    const unsigned* __restrict__ eaPk,    // [E][8] u32 (14 f16)
    const float* __restrict__ Wi,         // [300,147] fp32 (bond cols 133..146)
    unsigned* __restrict__ out,           // nei [N][152] u32 pairs
    int N)
{
    const int p = threadIdx.x;
    f16x2 wpk[14];
    if (p < 150) {
#pragma unroll
        for (int k = 0; k < 14; ++k)
            wpk[k] = (f16x2){(f16)Wi[(2 * p) * 147 + 133 + k],
                             (f16)Wi[(2 * p + 1) * 147 + 133 + k]};
    }
    const f16x2 zero2 = (f16x2){(f16)0.f, (f16)0.f};

    const int a0 = blockIdx.x * APB;
    const int a1 = min(a0 + APB, N);
    for (int a = a0; a < a1; ++a) {
        const int beg = rowPtr[a];
        const int end = rowPtr[a + 1];
        float acc0 = 0.f, acc1 = 0.f;
        if (p < 150) {
#pragma unroll 2
            for (int j = beg; j < end; ++j) {
                const int s = csrc[j];
                const unsigned* row = packed + (size_t)s * (PSTR / 2);
                const unsigned u0 = row[p];
                unsigned u1 = 0, u2 = 0;
                if (NSLOTS > 1) u1 = row[p + 150];
                if (NSLOTS > 2) u2 = row[p + 300];
                const unsigned* eq = eaPk + (size_t)j * 8;
                f16x2 ebA = zero2, ebB = zero2;
#pragma unroll
                for (int k = 0; k < 7; ++k) {
                    const f16x2 e2 = u2h(eq[k]);
                    ebA += (f16x2){e2.x, e2.x} * wpk[2 * k];
                    ebB += (f16x2){e2.y, e2.y} * wpk[2 * k + 1];
                }
                f16x2 m = __builtin_elementwise_max(u2h(u0) + (ebA + ebB), zero2);
                if (NSLOTS > 1) m = __builtin_elementwise_max(m + u2h(u1), zero2);
                if (NSLOTS > 2) m = __builtin_elementwise_max(m + u2h(u2), zero2);
                acc0 += (float)m.x;
                acc1 += (float)m.y;
            }
        }
        if (p < NEIP / 2)
            out[(size_t)a * (NEIP / 2) + p] = (p < 150) ? pk16(acc0, acc1) : 0u;
    }
}

// ---------------------------------------------------------------------------
// mol_pool: mol[b,:300] = sum of atom_h rows (f16, stride PSTR) with batch==b
// ---------------------------------------------------------------------------
__global__ __launch_bounds__(256) void mol_pool(
    const f16* __restrict__ ah,       // packed slot1: [N] rows stride 900
    const int* __restrict__ batch,    // [N], sorted
    float* __restrict__ mol,          // [B,300]
    int N)
{
    const int b = blockIdx.x;
    int lo = 0, hi = N;
    while (lo < hi) { int mid = (lo + hi) >> 1; if (batch[mid] < b) lo = mid + 1; else hi = mid; }
    const int start = lo;
    hi = N;
    while (lo < hi) { int mid = (lo + hi) >> 1; if (batch[mid] < b + 1) lo = mid + 1; else hi = mid; }
    const int end = lo;

    for (int h = threadIdx.x; h < HID; h += 256) {
        float s = 0.f;
        for (int a = start; a < end; ++a) s += (float)ah[(size_t)a * PSTR + h];
        mol[(size_t)b * HID + h] = s;
    }
}

// ---------------------------------------------------------------------------
__global__ __launch_bounds__(64) void ffn2_k(
    const f16* __restrict__ h1,       // [B][304] f16
    const float* __restrict__ w2,     // [300]
    const float* __restrict__ b2, float* __restrict__ out, int B)
{
    const int b = blockIdx.x;
    float s = 0.f;
    for (int k = threadIdx.x; k < HID; k += 64)
        s += (float)h1[(size_t)b * NEIP + k] * w2[k];
#pragma unroll
    for (int off = 32; off > 0; off >>= 1) s += __shfl_down(s, off);
    if (threadIdx.x == 0) out[b] = s + b2[0];
}

// ---------------------------------------------------------------------------
extern "C" void kernel_launch(void* const* d_in, const int* in_sizes, int n_in,
                              void* d_out, int out_size, void* d_ws, size_t ws_size,
                              hipStream_t stream)
{
    float* outp = (float*)d_out;
    const int fillBlocks = (out_size + 255) / 256;

    if (n_in < 12) {
        fill_f32<<<fillBlocks, 256, 0, stream>>>(outp, out_size, 2.0e6f + n_in);
        return;
    }

    const int N = in_sizes[0] / 133;   // atoms
    const int E = in_sizes[1] / 2;     // edges
    const int B = out_size;            // molecules

    const long long expect[12] = {
        (long long)N * 133, (long long)E * 2, (long long)E * 14, N,
        300LL * 147, 300LL * 300, 300LL * 433, 300,
        300LL * 300, 300, 300, 1 };
    for (int i = 0; i < 12; ++i) {
        if ((long long)in_sizes[i] != expect[i]) {
            fill_f32<<<fillBlocks, 256, 0, stream>>>(outp, out_size,
                                                     3.0e6f + 1.0e4f * i);
            return;
        }
    }

    const int G = (N + 1023) / 1024;   // scan blocks (N=100K -> 98)
    if (G > 1024) {
        fill_f32<<<fillBlocks, 256, 0, stream>>>(outp, out_size, 4.0e6f);
        return;
    }

    // ---- workspace layout ---------------------------------------------------
    char* basep = (char*)d_ws;
    auto align16 = [](size_t v) { return (v + 15) & ~(size_t)15; };
    const size_t packedB = align16((size_t)N * PSTR * sizeof(f16));
    const size_t neiB    = align16((size_t)N * NEIP * sizeof(f16));
    const size_t wSmall  = align16(320 * 144 * sizeof(f16));
    const size_t wBig    = align16(320 * 304 * sizeof(f16));
    const size_t molB    = align16((size_t)B * HID * sizeof(float));
    const size_t h1B     = align16((size_t)B * NEIP * sizeof(f16));
    const size_t rpB     = align16((size_t)(N + 1) * sizeof(int));
    const size_t curB    = align16((size_t)N * sizeof(int));
    const size_t csrcB   = align16((size_t)E * sizeof(int));
    const size_t eaB     = align16((size_t)E * 8 * sizeof(unsigned));
    const size_t bsB     = align16(1024 * sizeof(int));
    const size_t need = packedB + neiB + 2 * wSmall + 3 * wBig
                      + molB + h1B + rpB + 2 * curB + csrcB + eaB + 2 * bsB;

    if (ws_size < need) {
        fill_f32<<<fillBlocks, 256, 0, stream>>>(outp, out_size,
                                                 (float)(ws_size >> 20));
        return;
    }

    const float* x     = (const float*)d_in[0];
    const int*   ei    = (const int*)d_in[1];
    const float* ea    = (const float*)d_in[2];
    const int*   batch = (const int*)d_in[3];
    const float* W_i   = (const float*)d_in[4];
    const float* W_h   = (const float*)d_in[5];
    const float* W_o   = (const float*)d_in[6];
    const float* W_ob  = (const float*)d_in[7];
    const float* f1w   = (const float*)d_in[8];
    const float* f1b   = (const float*)d_in[9];
    const float* f2w   = (const float*)d_in[10];
    const float* f2b   = (const float*)d_in[11];
    const int* src = ei;
    const int* tgt = ei + E;

    char* cp = basep;
    f16* packed = (f16*)cp;         cp += packedB;
    f16* nei    = (f16*)cp;         cp += neiB;
    f16* WiA    = (f16*)cp;         cp += wSmall;
    f16* Wh     = (f16*)cp;         cp += wBig;
    f16* WoA    = (f16*)cp;         cp += wSmall;
    f16* WoB    = (f16*)cp;         cp += wBig;
    f16* Wf1    = (f16*)cp;         cp += wBig;
    float* mol  = (float*)cp;       cp += molB;
    f16* h1     = (f16*)cp;         cp += h1B;
    int* rowPtr = (int*)cp;         cp += rpB;
    int* cursor = (int*)cp;         cp += curB;
    int* deg    = (int*)cp;         cp += curB;
    int* csrc   = (int*)cp;         cp += csrcB;
    unsigned* eaPk = (unsigned*)cp; cp += eaB;
    int* bsum   = (int*)cp;         cp += bsB;
    int* boff   = (int*)cp;         cp += bsB;

    f16* xa_s  = packed;          // slot 0
    f16* hn0_s = packed + 300;    // slot 1 (later atom_h)
    f16* hn1_s = packed + 600;    // slot 2

    const unsigned* packed_u = (const unsigned*)packed;
    unsigned*       nei_u    = (unsigned*)nei;

    const int gAtom = (N + 127) / 128;
    const int gMolG = (B + 127) / 128;
    const int gEdge = (N + APB - 1) / APB;

    // --- CSR build (+ permuted f16 bond features) ---
    zero_i32<<<128, 256, 0, stream>>>(deg, N);
    hist_tgt<<<1024, 256, 0, stream>>>(tgt, deg, E, N);
    scan_p1<<<G, 1024, 0, stream>>>(deg, bsum, N);
    scan_p2<<<1, 1024, 0, stream>>>(bsum, boff, G, rowPtr + N, E);
    scan_p3<<<G, 1024, 0, stream>>>(deg, boff, rowPtr, cursor, N);
    scatter_e<<<1024, 256, 0, stream>>>(src, tgt, ea, cursor, csrc, eaPk, E, N);

    // --- weights -> padded f16 ---
    cvt_pad_f16<<<64,  256, 0, stream>>>(WiA, W_i,       300, 147, 133, 144, 320);
    cvt_pad_f16<<<128, 256, 0, stream>>>(Wh,  W_h,       300, 300, 300, 304, 320);
    cvt_pad_f16<<<64,  256, 0, stream>>>(WoA, W_o,       300, 433, 133, 144, 320);
    cvt_pad_f16<<<128, 256, 0, stream>>>(WoB, W_o + 133, 300, 433, 300, 304, 320);
    cvt_pad_f16<<<128, 256, 0, stream>>>(Wf1, f1w,       300, 300, 300, 304, 320);

    // 1. xa = x @ W_i[:, :133]^T -> packed slot0
    gemm_mfma<<<gAtom, 512, 0, stream>>>(x, 133, 0, 133, WiA, 144,
        nullptr, 0, 0, 0, nullptr, 0, nullptr, xa_s, PSTR, N, 0);
    // 2. nei0 = segsum(m0)
    edge_csr<1><<<gEdge, 192, 0, stream>>>(packed_u, rowPtr, csrc, eaPk, W_i,
                                           nei_u, N);
    // 3. hn0 = nei0 @ W_h^T -> packed slot1
    gemm_mfma<<<gAtom, 512, 0, stream>>>(nei, NEIP, 1, NEIP, Wh, 304,
        nullptr, 0, 0, 0, nullptr, 0, nullptr, hn0_s, PSTR, N, 0);
    // 4. nei1 = segsum(m1)
    edge_csr<2><<<gEdge, 192, 0, stream>>>(packed_u, rowPtr, csrc, eaPk, W_i,
                                           nei_u, N);
    // 5. hn1 = nei1 @ W_h^T -> packed slot2
    gemm_mfma<<<gAtom, 512, 0, stream>>>(nei, NEIP, 1, NEIP, Wh, 304,
        nullptr, 0, 0, 0, nullptr, 0, nullptr, hn1_s, PSTR, N, 0);
    // 6. atom_msg = segsum(m2)
    edge_csr<3><<<gEdge, 192, 0, stream>>>(packed_u, rowPtr, csrc, eaPk, W_i,
                                           nei_u, N);
    // 7. atom_h = relu(x @ WoA^T + msg @ WoB^T + b) -> packed slot1
    gemm_mfma<<<gAtom, 512, 0, stream>>>(x, 133, 0, 133, WoA, 144,
        nei, NEIP, 1, NEIP, WoB, 304, W_ob, hn0_s, PSTR, N, 1);
    // 8. mol[b] = segment_sum(atom_h)
    mol_pool<<<B, 256, 0, stream>>>(hn0_s, batch, mol, N);
    // 9. h1 = relu(mol @ ffn1^T + b1)   (MFMA, f16 out)
    gemm_mfma<<<gMolG, 512, 0, stream>>>(mol, 300, 0, 300, Wf1, 304,
        nullptr, 0, 0, 0, nullptr, 0, f1b, h1, NEIP, B, 1);
    // 10. out = h1 @ ffn2^T + b2
    ffn2_k<<<B, 64, 0, stream>>>(h1, f2w, f2b, outp, B);
}